// Round 6
// baseline (372.828 us; speedup 1.0000x reference)
//
#include <hip/hip_runtime.h>

#define TLEN  4096
#define NROWS 4096
#define RPB   32            // rows per block (owned by the scan wave)
#define K     32            // timesteps per chunk
#define NC    (TLEN / K)    // 128 chunks
#define SGSL  (16 * 64)     // coef slot: 16 tp-granules x 64 lanes (float4 units)
#define STP   34            // staging pitch (dwords): 32 steps + 2 pad (even -> b64-aligned, 2-way banks max)
#define STSL  (64 * STP)    // output-staging slot (floats)
#define UN    8             // exact-path unroll

__device__ __forceinline__ float fexp2(float x) { return __builtin_amdgcn_exp2f(x); }
__device__ __forceinline__ float frcp(float x)  { return __builtin_amdgcn_rcpf(x); }
__device__ __forceinline__ float sigz(float z)  { return frcp(1.0f + fexp2(z)); }

// Swap adjacent lanes (lane ^ 1): DPP quad_perm [1,0,3,2].
__device__ __forceinline__ float lane_swap1(float v) {
    int r = __builtin_amdgcn_update_dpp(0, __float_as_int(v), 0xB1, 0xF, 0xF, true);
    return __int_as_float(r);
}

// ---------------------------------------------------------------------------
// Round-5 structure (resubmission; round-5 bench was an infra failure, no
// dispatch ran). Law (r0-r4): wall = scan-wave stream-length x ~6.9 cyc,
// trans-on-chain ops cost ~3-4x a VALU slot (r4 lesson) -> sigma stays Taylor
// (off-chain), deg-1 now, with exact resync every 16 steps.
//
//   wave 0 (scan):  per step-pair (2 steps):
//       2 x { m=fma(a,x,b); t1v=fma(Gn1,x,P1); t2v=fma(Gn2,x,P2);
//             b2=fma(sig,t1v,m); sc=DPP(sig); dx=fma(sc,t2v,b2); x+=dx;
//             dz=sdz*dx; sig=fma(u,dz,sig) }          // deg-1 Taylor
//       + u=fma(-sig,sig,sig) once + one ds_write_b64 (x_t,x_t+1)
//       + one ds_read_b128 (coefs for 2 steps)  ~= 10.5 slots/step.
//     Exact sigz resync every 16 steps bounds deg-1 drift (<~1e-4 in sig).
//   wave 1 (produce): input sigmoids+premuls for chunk c+1. Lane l handles
//     (row l>>1, dir l&1) -> writes sl[j*64+l]: consecutive lanes ->
//     conflict-free ds_write_b128 (fixes r4's 2.1M bank conflicts).
//   wave 2 (flush):  staged outputs of chunk c-1 -> HBM, 256B runs.
//   Three waves land on 3 different SIMDs; helper streams (~265 / ~100
//   slots/chunk) hide fully under the scan's ~370.
// ---------------------------------------------------------------------------
__device__ void run_fast(const float* __restrict__ inp, const float* __restrict__ prm,
                         float* __restrict__ out,
                         float4* __restrict__ sgbuf,  // [2][16 tp][64 lane] float4
                         float*  __restrict__ st) {   // [2][64 lane][STP]
    const int tid  = threadIdx.x;
    const int wid  = tid >> 6;          // 0 = scan, 1 = produce, 2 = flush
    const int lane = tid & 63;
    const int R0   = blockIdx.x * RPB;
    const float L2E = 1.4426950408889634f;
    float2* __restrict__ out2 = (float2*)out;

    if (wid == 1) {
        // ---------------- produce wave ----------------
        const int row = lane >> 1, dir = lane & 1;   // dir 0 = x ('ax'), 1 = y ('by')
        const float sd = dir ? prm[8] : prm[4];
        const float mn = dir ? prm[7] : prm[3];
        const float c1 = -sd * L2E, c0 = sd * mn * L2E;
        const float gA = dir ? (prm[6] / prm[1]) : (prm[2] / prm[0]);
        const float P  = gA * (dir ? prm[9] : prm[5]);
        const float Gn = -gA;
        const float4* __restrict__ src = (const float4*)inp + (size_t)(R0 + row) * (TLEN / 2);

        auto produce = [&](int c) {   // coef pairs of chunk c -> sgbuf slot c&1
            float4* sl = sgbuf + ((c & 1) ? SGSL : 0);
            const int base = c * 16;
#pragma unroll
            for (int j = 0; j < 16; ++j) {
                float4 v = src[base + j];            // (a_t, b_t, a_t+1, b_t+1)
                float p0 = dir ? v.y : v.x;
                float p1 = dir ? v.w : v.z;
                float s0 = sigz(__builtin_fmaf(c1, p0, c0));
                float s1 = sigz(__builtin_fmaf(c1, p1, c0));
                float4 o; o.x = Gn * s0; o.y = P * s0;
                          o.z = Gn * s1; o.w = P * s1;
                sl[j * 64 + lane] = o;               // consecutive lanes: conflict-free
            }
        };

        produce(0);
        __syncthreads();
        for (int c = 0; c < NC; ++c) {
            if (c + 1 < NC) produce(c + 1);
            __syncthreads();
        }
    } else if (wid == 2) {
        // ---------------- flush wave ----------------
        auto flush = [&](int c) {     // st slot c&1 -> out, 256B coalesced runs
            const float* sl = st + ((c & 1) ? STSL : 0);
            const int col = lane & 31;
#pragma unroll
            for (int j = 0; j < 16; ++j) {
                int ro = 2 * j + (lane >> 5);
                float2 v;
                v.x = sl[(2 * ro)     * STP + col];  // x of row ro, step col
                v.y = sl[(2 * ro + 1) * STP + col];  // y of row ro, step col
                out2[(size_t)(R0 + ro) * TLEN + (size_t)c * K + col] = v;
            }
        };

        __syncthreads();
        for (int c = 0; c < NC; ++c) {
            if (c >= 1) flush(c - 1);
            __syncthreads();
        }
        flush(NC - 1);                         // epilogue: last chunk
    } else {
        // ---------------- scan wave ----------------
        // Lane pair (2r, 2r+1) owns row r: even lane = x, odd = y.
        const int par = lane & 1;
        const int sfB = par ? 22 : 18, t2B = par ? 10 : 14;
        const float ic  = 1.0f / prm[par];
        const float g1  = prm[sfB] * ic, P1 = g1 * prm[sfB + 3], Gn1 = -g1; // self
        const float g2  = prm[t2B] * ic, P2 = g2 * prm[t2B + 3], Gn2 = -g2; // cross
        const float sdz = prm[sfB + 2];
        const float c1s = -sdz * L2E, c0s = sdz * prm[sfB + 1] * L2E;

        float x   = par ? 1.0f : 0.0f;
        float sig = sigz(__builtin_fmaf(c1s, x, c0s));
        float u   = __builtin_fmaf(-sig, sig, sig);   // sig*(1-sig)

        auto resync = [&]() {                         // exact sigma (off-chain cost)
            sig = sigz(__builtin_fmaf(c1s, x, c0s));
            u   = __builtin_fmaf(-sig, sig, sig);
        };

        __syncthreads();                       // sgbuf slot 0 ready
        for (int c = 0; c < NC; ++c) {
            const float4* lb = sgbuf + ((c & 1) ? SGSL : 0);
            float* wp = st + ((c & 1) ? STSL : 0) + lane * STP;
            float4 f0 = lb[lane];
            float4 f1 = lb[64 + lane];
#pragma unroll
            for (int tp = 0; tp < 16; ++tp) {
                float4 f = f0; f0 = f1;
                if (tp < 14) f1 = lb[(tp + 2) * 64 + lane];   // 2-granule lookahead
                // step A (coefs f.x=Gn*sgin, f.y=P*sgin premade by produce wave)
                float m   = __builtin_fmaf(f.x, x, f.y);
                float t1v = __builtin_fmaf(Gn1, x, P1);
                float t2v = __builtin_fmaf(Gn2, x, P2);
                float b2  = __builtin_fmaf(sig, t1v, m);
                float sc  = lane_swap1(sig);
                float dxa = __builtin_fmaf(sc, t2v, b2);
                x = x + dxa;
                float xa  = x;
                float dza = sdz * dxa;
                sig = __builtin_fmaf(u, dza, sig);            // deg-1 Taylor
                // step B
                float m2   = __builtin_fmaf(f.z, x, f.w);
                float t1v2 = __builtin_fmaf(Gn1, x, P1);
                float t2v2 = __builtin_fmaf(Gn2, x, P2);
                float b22  = __builtin_fmaf(sig, t1v2, m2);
                float sc2  = lane_swap1(sig);
                float dxb  = __builtin_fmaf(sc2, t2v2, b22);
                x = x + dxb;
                float dzb = sdz * dxb;
                sig = __builtin_fmaf(u, dzb, sig);            // deg-1 Taylor
                u   = __builtin_fmaf(-sig, sig, sig);         // refresh once / pair
                float2 w2; w2.x = xa; w2.y = x;
                *(float2*)(wp + 2 * tp) = w2;                 // ds_write_b64
                if (tp == 7) resync();                        // mid-chunk resync
            }
            resync();                                         // end-chunk resync
            __syncthreads();                   // hand slots to helpers / get next
        }
    }
}

// ---------------------------------------------------------------------------
// Exact fallback for non-shared params (proven path; 192-thr blocks,
// threads beyond row 4095 idle).
// ---------------------------------------------------------------------------
struct LaneConst {
    float c1_in, c0_in, c1_sf, c0_sf, c1_ot, c0_ot;
    float gS_in, gS_cr, gS_sf, gP_in, gP_cr, gP_sf;
};

__device__ __forceinline__ float do_step_exact(float s, float pre_in, const LaneConst& k) {
    float sig_in = sigz(__builtin_fmaf(k.c1_in, pre_in, k.c0_in));
    float sig_sf = sigz(__builtin_fmaf(k.c1_sf, s, k.c0_sf));
    float sig_ot = sigz(__builtin_fmaf(k.c1_ot, s, k.c0_ot));
    float sig_cr = lane_swap1(sig_ot);
    float S = __builtin_fmaf(k.gS_in, sig_in, __builtin_fmaf(k.gS_cr, sig_cr, k.gS_sf * sig_sf));
    float P = __builtin_fmaf(k.gP_in, sig_in, __builtin_fmaf(k.gP_cr, sig_cr, k.gP_sf * sig_sf));
    return s + __builtin_fmaf(S, -s, P);
}

__device__ void run_exact(const float* __restrict__ inp, const float* __restrict__ prm,
                          float* __restrict__ out) {
    const int tid = blockIdx.x * 192 + threadIdx.x;
    const int row = tid >> 1;
    if (row >= NROWS) return;
    const int par = tid & 1;
    const float L2E = 1.4426950408889634f;
    const int inB = par ? 6 : 2, sfB = par ? 22 : 18, otB = par ? 14 : 10, crB = par ? 10 : 14;
    const float invc = 1.0f / prm[par];
    LaneConst k;
    float sd = prm[inB + 2], mn = prm[inB + 1];
    k.c1_in = -sd * L2E; k.c0_in = sd * mn * L2E;
    sd = prm[sfB + 2]; mn = prm[sfB + 1];
    k.c1_sf = -sd * L2E; k.c0_sf = sd * mn * L2E;
    sd = prm[otB + 2]; mn = prm[otB + 1];
    k.c1_ot = -sd * L2E; k.c0_ot = sd * mn * L2E;
    k.gS_in = prm[inB] * invc; k.gP_in = k.gS_in * prm[inB + 3];
    k.gS_sf = prm[sfB] * invc; k.gP_sf = k.gS_sf * prm[sfB + 3];
    k.gS_cr = prm[crB] * invc; k.gP_cr = k.gS_cr * prm[crB + 3];

    const float4* __restrict__ src = (const float4*)inp + (size_t)row * (TLEN / 2);
    float* __restrict__ dst = out + (size_t)row * (TLEN * 2) + par;
    float s = par ? 1.0f : 0.0f;

    float4 cur[UN], nxt[UN];
#pragma unroll
    for (int j = 0; j < UN; ++j) cur[j] = src[j];
    const int NIT = TLEN / (2 * UN);
    for (int it = 0; it < NIT; ++it) {
        if (it + 1 < NIT) {
#pragma unroll
            for (int j = 0; j < UN; ++j) nxt[j] = src[(it + 1) * UN + j];
        }
        float* dptr = dst + it * (UN * 4);
#pragma unroll
        for (int j = 0; j < UN; ++j) {
            float4 f = cur[j];
            s = do_step_exact(s, par ? f.y : f.x, k);
            dptr[j * 4] = s;
            s = do_step_exact(s, par ? f.w : f.z, k);
            dptr[j * 4 + 2] = s;
        }
#pragma unroll
        for (int j = 0; j < UN; ++j) cur[j] = nxt[j];
    }
}

__global__ __launch_bounds__(192, 1)
void memcell_scan(const float* __restrict__ inp, const float* __restrict__ prm,
                  float* __restrict__ out) {
    __shared__ float4 sgbuf[2 * SGSL];   // 32 KB coef double-buffer
    __shared__ float  st[2 * STSL];      // 17.4 KB output staging double-buffer

    // Fast-path guard:
    //  - shared (mean,std) between self & cross state dirs (xx==xy, yy==yx)
    //  - g >= 0, caps > 0        -> states stay in hull{s0, pots}
    //  - sum(g/cap) <= 0.25      -> no overshoot
    //  - wb = std*max|dx| <= 0.02 -> deg-1 sigma-Taylor valid
    //    (exact resync every 16 steps bounds drift to ~1e-4)
    //  - |z| <= 20               -> sigz well-conditioned
    const bool shared = (prm[11] == prm[19]) && (prm[12] == prm[20]) &&
                        (prm[15] == prm[23]) && (prm[16] == prm[24]);
    const float capx = prm[0], capy = prm[1];
    const bool gpos = prm[2] >= 0.f && prm[6] >= 0.f && prm[10] >= 0.f &&
                      prm[14] >= 0.f && prm[18] >= 0.f && prm[22] >= 0.f &&
                      capx > 0.f && capy > 0.f;
    const float sx = (prm[2] + prm[14] + prm[18]) / capx;
    const float sy = (prm[6] + prm[10] + prm[22]) / capy;
    const float lox = fminf(0.f, fminf(prm[5], fminf(prm[17], prm[21])));
    const float hix = fmaxf(0.f, fmaxf(prm[5], fmaxf(prm[17], prm[21])));
    const float loy = fminf(1.f, fminf(prm[9], fminf(prm[13], prm[25])));
    const float hiy = fmaxf(1.f, fmaxf(prm[9], fmaxf(prm[13], prm[25])));
    const float wbx = prm[20] * sx * (hix - lox), wby = prm[24] * sy * (hiy - loy);
    const float zmx = prm[20] * fmaxf(fabsf(lox - prm[19]), fabsf(hix - prm[19]));
    const float zmy = prm[24] * fmaxf(fabsf(loy - prm[23]), fabsf(hiy - prm[23]));
    const bool fast = shared && gpos && sx <= 0.25f && sy <= 0.25f &&
                      wbx <= 0.02f && wby <= 0.02f && zmx <= 20.f && zmy <= 20.f;
    if (fast) {
        run_fast(inp, prm, out, sgbuf, st);
    } else {
        run_exact(inp, prm, out);
    }
}

extern "C" void kernel_launch(void* const* d_in, const int* in_sizes, int n_in,
                              void* d_out, int out_size, void* d_ws, size_t ws_size,
                              hipStream_t stream) {
    (void)in_sizes; (void)n_in; (void)d_ws; (void)ws_size; (void)out_size;
    const float* inp = (const float*)d_in[0];
    const float* prm = (const float*)d_in[1];
    float* out = (float*)d_out;
    memcell_scan<<<dim3(NROWS / RPB), dim3(192), 0, stream>>>(inp, prm, out);
}